// Round 2
// baseline (308.597 us; speedup 1.0000x reference)
//
#include <hip/hip_runtime.h>

#define BSZ 4
#define NH 16
#define SL 1024
#define DH 64

typedef __bf16 bf16x8 __attribute__((ext_vector_type(8)));
typedef float  f32x4  __attribute__((ext_vector_type(4)));

static __device__ __forceinline__ __bf16 f2bf(float f) {
    return (__bf16)f;                          // HW RNE f32->bf16 cvt
}

static __device__ __forceinline__ void mfma16(f32x4& d, bf16x8 a, bf16x8 b) {
    d = __builtin_amdgcn_mfma_f32_16x16x32_bf16(a, b, d, 0, 0, 0);
}

// Block: 4 waves / 256 threads. Handles 16 q-rows x full 1024 cols of one (b,h).
// Wave w owns cols [w*256, w*256+256): 16 MFMA 16x16 tiles.
__global__ void __launch_bounds__(256)
attn_fused(const float* __restrict__ qg0, const float* __restrict__ kg0,
           const float* __restrict__ vg0, const float* __restrict__ pg0,
           const float* __restrict__ scale_p,
           float* __restrict__ og0, float* __restrict__ wg0, float* __restrict__ sg0)
{
    // Manually aliased LDS pool:
    //   q_s : float[16][68]      @ 0      (4352 B)   } o_s[4][16][68] (17408 B)
    //   w_s : ushort[16][1026]   @ 4352   (32832 B)  }   aliases these after PV
    //   red : float[2][4][16]    @ 37184  (512 B)
    __shared__ __align__(16) char smem[37696];
    float          (*q_s)[68]   = (float (*)[68])smem;
    unsigned short (*w_s)[1026] = (unsigned short (*)[1026])(smem + 4352);
    float           *red        = (float*)(smem + 37184);
    float          (*o_s)[16][68] = (float (*)[16][68])smem;

    const int bid     = blockIdx.x;
    const int logical = (bid & 7) * 512 + (bid >> 3);   // XCD swizzle, bijective (4096%8==0)
    const int bh      = logical >> 6;                    // 64 q-tiles per (b,h)
    const int qbase   = (logical & 63) << 4;

    const int tid  = threadIdx.x;
    const int wid  = tid >> 6;
    const int lane = tid & 63;
    const int l15  = lane & 15;
    const int lhi  = lane >> 4;
    const int colbase = wid << 8;

    const float scale = *scale_p;

    const float* qg = qg0 + (size_t)bh * SL * DH;
    const float* kg = kg0 + (size_t)bh * DH * SL;   // k is [d][s]
    const float* vg = vg0 + (size_t)bh * SL * DH;
    const float* pg = pg0 + (size_t)bh * SL * SL;
    float* og = og0 + (size_t)bh * SL * DH;
    float* wg = wg0 + (size_t)bh * SL * SL;
    float* sg = sg0 + (size_t)bh * SL * SL;

    // ---- stage Q tile (16x64 f32), coalesced float4 ----
    {
        const int r  = tid >> 4;
        const int c4 = (tid & 15) << 2;
        const float4 t = *(const float4*)(qg + (size_t)(qbase + r) * DH + c4);
        *(float4*)&q_s[r][c4] = t;
    }
    __syncthreads();

    // ---- Q fragments (A operand): A[m=l15][k], k = 4*lhi + (j&3) + 16*(j>>2) ----
    bf16x8 qf[2];
#pragma unroll
    for (int ks = 0; ks < 2; ++ks)
#pragma unroll
        for (int j = 0; j < 8; ++j) {
            const int d = ks * 32 + 4 * lhi + (j & 3) + 16 * (j >> 2);
            qf[ks][j] = f2bf(q_s[l15][d]);
        }

    // ---- QK^T: acc[t] = rows[qbase..+16) x cols[colbase+16t..+16) ----
    f32x4 acc[16];
#pragma unroll
    for (int t = 0; t < 16; ++t) { f32x4 z = {0.f, 0.f, 0.f, 0.f}; acc[t] = z; }

#pragma unroll
    for (int t = 0; t < 16; ++t) {
        const int n = colbase + t * 16 + l15;
#pragma unroll
        for (int ks = 0; ks < 2; ++ks) {
            bf16x8 kf;
#pragma unroll
            for (int j = 0; j < 8; ++j) {
                const int d = ks * 32 + 4 * lhi + (j & 3) + 16 * (j >> 2);
                kf[j] = f2bf(kg[(size_t)d * SL + n]);   // B[k=d][n], 64B segments
            }
            mfma16(acc[t], qf[ks], kf);
        }
    }

    // ---- scores = acc*scale + prev ; write scores; keep live in acc ----
    // D layout: col = l15, row = 4*lhi + i
#pragma unroll
    for (int t = 0; t < 16; ++t) {
        const int col = colbase + t * 16 + l15;
#pragma unroll
        for (int i = 0; i < 4; ++i) {
            const int row = qbase + 4 * lhi + i;
            const float s = acc[t][i] * scale + pg[(size_t)row * SL + col];
            sg[(size_t)row * SL + col] = s;
            acc[t][i] = s;
        }
    }

    // ---- softmax over full rows (cols split across 4 waves) ----
    float mx[4];
#pragma unroll
    for (int i = 0; i < 4; ++i) {
        float m = acc[0][i];
#pragma unroll
        for (int t = 1; t < 16; ++t) m = fmaxf(m, acc[t][i]);
#pragma unroll
        for (int off = 1; off < 16; off <<= 1) m = fmaxf(m, __shfl_xor(m, off, 64));
        if (l15 == 0) red[(0 * 4 + wid) * 16 + 4 * lhi + i] = m;
    }
    __syncthreads();
#pragma unroll
    for (int i = 0; i < 4; ++i) {
        const int r = 4 * lhi + i;
        float m = red[0 * 16 + r];
#pragma unroll
        for (int w = 1; w < 4; ++w) m = fmaxf(m, red[w * 16 + r]);
        mx[i] = m;
    }
    float sm[4] = {0.f, 0.f, 0.f, 0.f};
#pragma unroll
    for (int t = 0; t < 16; ++t)
#pragma unroll
        for (int i = 0; i < 4; ++i) {
            const float p = __expf(acc[t][i] - mx[i]);
            acc[t][i] = p;
            sm[i] += p;
        }
#pragma unroll
    for (int i = 0; i < 4; ++i) {
#pragma unroll
        for (int off = 1; off < 16; off <<= 1) sm[i] += __shfl_xor(sm[i], off, 64);
        if (l15 == 0) red[(1 * 4 + wid) * 16 + 4 * lhi + i] = sm[i];
    }
    __syncthreads();
    float inv[4];
#pragma unroll
    for (int i = 0; i < 4; ++i) {
        const int r = 4 * lhi + i;
        inv[i] = 1.f / (red[(4 + 0) * 16 + r] + red[(4 + 1) * 16 + r] +
                        red[(4 + 2) * 16 + r] + red[(4 + 3) * 16 + r]);
    }

    // ---- weights: f32 to global, bf16 to LDS (layout for PV A-operand) ----
#pragma unroll
    for (int t = 0; t < 16; ++t) {
        const int col = colbase + t * 16 + l15;
#pragma unroll
        for (int i = 0; i < 4; ++i) {
            const int rloc = 4 * lhi + i;
            const float wv = acc[t][i] * inv[i];
            wg[(size_t)(qbase + rloc) * SL + col] = wv;
            w_s[rloc][col] = __builtin_bit_cast(unsigned short, f2bf(wv));
        }
    }
    __syncthreads();

    // ---- PV: partial out[16 x 64] over this wave's 256 cols (k-dim) ----
    f32x4 oacc[4];
#pragma unroll
    for (int nt = 0; nt < 4; ++nt) { f32x4 z = {0.f, 0.f, 0.f, 0.f}; oacc[nt] = z; }

#pragma unroll
    for (int kt = 0; kt < 8; ++kt) {
        bf16x8 af;   // A[m=l15][k]: W[l15][colbase + kt*32 + kmap]
#pragma unroll
        for (int jp = 0; jp < 4; ++jp) {
            const int cl = colbase + kt * 32 + 4 * lhi + 2 * (jp & 1) + 16 * (jp >> 1);
            const unsigned u = *(const unsigned*)&w_s[l15][cl];  // 2 adjacent bf16
            af[2 * jp]     = __builtin_bit_cast(__bf16, (unsigned short)(u & 0xffffu));
            af[2 * jp + 1] = __builtin_bit_cast(__bf16, (unsigned short)(u >> 16));
        }
#pragma unroll
        for (int nt = 0; nt < 4; ++nt) {
            bf16x8 bf;   // B[k=s][n=d]: v[s][nt*16+l15]
#pragma unroll
            for (int j = 0; j < 8; ++j) {
                const int s = colbase + kt * 32 + 4 * lhi + (j & 3) + 16 * (j >> 2);
                bf[j] = f2bf(vg[(size_t)s * DH + nt * 16 + l15]);
            }
            mfma16(oacc[nt], af, bf);
        }
    }
    __syncthreads();   // w_s reads done before o_s aliases it

    // ---- cross-wave reduce of PV partials, coalesced f32x4 store ----
#pragma unroll
    for (int nt = 0; nt < 4; ++nt)
#pragma unroll
        for (int i = 0; i < 4; ++i)
            o_s[wid][4 * lhi + i][nt * 16 + l15] = oacc[nt][i];
    __syncthreads();
    {
        const int r  = tid >> 4;
        const int c4 = (tid & 15) << 2;
        float4 a = *(const float4*)&o_s[0][r][c4];
        const float4 b = *(const float4*)&o_s[1][r][c4];
        const float4 c = *(const float4*)&o_s[2][r][c4];
        const float4 d = *(const float4*)&o_s[3][r][c4];
        a.x += b.x + c.x + d.x;  a.y += b.y + c.y + d.y;
        a.z += b.z + c.z + d.z;  a.w += b.w + c.w + d.w;
        *(float4*)(og + (size_t)(qbase + r) * DH + c4) = a;
    }
}

extern "C" void kernel_launch(void* const* d_in, const int* in_sizes, int n_in,
                              void* d_out, int out_size, void* d_ws, size_t ws_size,
                              hipStream_t stream) {
    const float* q     = (const float*)d_in[0];
    const float* k     = (const float*)d_in[1];
    const float* v     = (const float*)d_in[2];
    const float* prev  = (const float*)d_in[3];
    const float* scale = (const float*)d_in[4];

    float* out  = (float*)d_out;                                   // (4,16,1024,64)
    float* wout = out  + (size_t)BSZ * NH * SL * DH;               // (4,16,1024,1024)
    float* sout = wout + (size_t)BSZ * NH * SL * SL;               // (4,16,1024,1024)

    const int nblocks = (BSZ * NH) * (SL / 16);   // 64 * 64 = 4096
    attn_fused<<<nblocks, 256, 0, stream>>>(q, k, v, prev, scale, out, wout, sout);
}